// Round 15
// baseline (347.174 us; speedup 1.0000x reference)
//
#include <hip/hip_runtime.h>
#include <hip/hip_bf16.h>

using bf16 = __hip_bfloat16;

constexpr int B = 8, C = 64, H = 256, W = 256;
constexpr int HWs = H * W;               // 65536
constexpr int NPIX = B * H * W;          // 524288
constexpr long long NELEM = (long long)B * C * H * W;  // 33554432
constexpr int CS = 32;
constexpr int Hd = 128, Wd = 128;
constexpr int HWd = Hd * Wd;             // 16384
constexpr int NDOWN = B * CS * HWd;      // 4194304
constexpr float EPS = 1e-6f;
constexpr float SCALE = 0.17677669529663687f;  // 32^-0.5

typedef __attribute__((ext_vector_type(8))) short short8v;
typedef __attribute__((ext_vector_type(8))) unsigned short ushort8v;
typedef __attribute__((ext_vector_type(4))) unsigned short ushort4v;
typedef __attribute__((ext_vector_type(4))) float f32x4;

__device__ __forceinline__ float b2f(bf16 v) { return __bfloat162float(v); }
__device__ __forceinline__ bf16 f2b(float v) { return __float2bfloat16(v); }
__device__ __forceinline__ unsigned short f2bu(float v) {
  bf16 t = __float2bfloat16(v);
  unsigned short u;
  __builtin_memcpy(&u, &t, 2);
  return u;
}
__device__ __forceinline__ float bu2f(unsigned short u) {
  bf16 t;
  __builtin_memcpy(&t, &u, 2);
  return __bfloat162float(t);
}
__device__ __forceinline__ short8v pack2(ushort4v a, ushort4v b) {
  short8v r;
  r[0] = (short)a[0]; r[1] = (short)a[1]; r[2] = (short)a[2]; r[3] = (short)a[3];
  r[4] = (short)b[0]; r[5] = (short)b[1]; r[6] = (short)b[2]; r[7] = (short)b[3];
  return r;
}

// ---- K1 v5: fused LayerNorm + q/k/v MFMA projections with DENSE writes.
// SINGLE per-wave slab (20.5 KB/block vs 40 KB): phases sequence through it
// (per-wave DS ordering, barrier-free) -> 4 blocks/CU instead of 3. ----
__global__ __launch_bounds__(256) void qkv_ln_kernel(
    const float* __restrict__ x0, const float* __restrict__ lnw,
    const float* __restrict__ lnb, const float* __restrict__ wq,
    const float* __restrict__ wk, const float* __restrict__ wv,
    unsigned short* __restrict__ xo, unsigned short* __restrict__ q0,
    unsigned short* __restrict__ q1, unsigned short* __restrict__ k0,
    unsigned short* __restrict__ v0, unsigned short* __restrict__ ksp,
    unsigned short* __restrict__ vsp) {
  __shared__ unsigned short sS[4][2560];   // one slab per wave
  int lane = threadIdx.x & 63, wid = threadIdx.x >> 6;
  int lr = lane & 15, lg = lane >> 4;
  unsigned short* S = &sS[wid][0];
  int seg = blockIdx.x * 4 + wid;          // 0..8191
  int p0 = seg * 64;
  int b = p0 >> 16;
  int hw0 = p0 & (HWs - 1);
  int r = hw0 >> 8, col0 = hw0 & 255;      // col0 multiple of 64
  float lwv[16], lbv[16];
#pragma unroll
  for (int ks = 0; ks < 2; ++ks)
#pragma unroll
    for (int j = 0; j < 8; ++j) {
      int c = ks * 32 + lg * 4 + (j & 3) + 16 * (j >> 2);
      lwv[ks * 8 + j] = lnw[c];
      lbv[ks * 8 + j] = lnb[c];
    }
  short8v bx[4][2];
#pragma unroll
  for (int st = 0; st < 4; ++st) {
    const float* xp = x0 + (size_t)b * C * HWs + hw0 + st * 16 + lr;
    float xv[16];
#pragma unroll
    for (int ks = 0; ks < 2; ++ks)
#pragma unroll
      for (int j = 0; j < 8; ++j) {
        int c = ks * 32 + lg * 4 + (j & 3) + 16 * (j >> 2);
        xv[ks * 8 + j] = xp[(size_t)c * HWs];
      }
    float s = 0.f, s2 = 0.f;
#pragma unroll
    for (int i = 0; i < 16; ++i) { s += xv[i]; s2 += xv[i] * xv[i]; }
    s += __shfl_xor(s, 16, 64); s += __shfl_xor(s, 32, 64);
    s2 += __shfl_xor(s2, 16, 64); s2 += __shfl_xor(s2, 32, 64);
    float mu = s * (1.f / 64);
    float var = s2 * (1.f / 64) - mu * mu;
    float rstd = rsqrtf(var + EPS);
#pragma unroll
    for (int ks = 0; ks < 2; ++ks)
#pragma unroll
      for (int j = 0; j < 8; ++j) {
        float xn = lwv[ks * 8 + j] * ((xv[ks * 8 + j] - mu) * rstd) + lbv[ks * 8 + j];
        bx[st][ks][j] = (short)f2bu(xn);
      }
  }
  int rr = (r - 4) & 255;
  int tokr = (rr & 7) * 8;
  int wrow = b * 1024 + (rr >> 3) * 32;
  auto win_store = [&](const unsigned short* src, unsigned short* dst) {
#pragma unroll
    for (int i = 0; i < 4; ++i) {
      int g = i * 4 + (lane >> 4);
      int tl = (lane >> 2) & 3, ch8 = lane & 3;
      int px = g * 4 + tl;
      int ccw = (col0 + px - 4) & 255;
      size_t wb = (size_t)(wrow + (ccw >> 3)) * 2048 +
                  (size_t)(tokr + (ccw & 7)) * 32 + ch8 * 8;
      ushort8v d = *(const ushort8v*)(src + px * 40 + ch8 * 8);
      *(ushort8v*)(dst + wb) = d;
    }
  };
  auto load_wfrag = [&](const float* wsrc, short8v wf[4][2]) {
#pragma unroll
    for (int mt = 0; mt < 4; ++mt)
#pragma unroll
      for (int ks = 0; ks < 2; ++ks) {
        int rowoff = (mt * 16 + lr) * 64 + ks * 32 + lg * 4;
        short8v t;
#pragma unroll
        for (int j = 0; j < 8; ++j) {
          int kj = (j & 3) + 16 * (j >> 2);
          t[j] = (short)f2bu(wsrc[rowoff + kj]);
        }
        wf[mt][ks] = t;
      }
  };
  f32x4 zero = {0.f, 0.f, 0.f, 0.f};
  // ---- phase X: LN'd x -> spatial, two 32-ch halves through the slab ----
#pragma unroll
  for (int half = 0; half < 2; ++half) {
#pragma unroll
    for (int st = 0; st < 4; ++st) {
      int px = st * 16 + lr;
#pragma unroll
      for (int j = 0; j < 8; ++j) {
        int c = lg * 4 + (j & 3) + 16 * (j >> 2);
        S[c * 80 + px] = (unsigned short)bx[st][half][j];
      }
    }
#pragma unroll
    for (int i = 0; i < 4; ++i) {
      int ch = i * 8 + (lane >> 3), pxg = lane & 7;
      ushort8v d = *(const ushort8v*)(S + ch * 80 + pxg * 8);
      *(ushort8v*)(xo + ((size_t)b * 64 + half * 32 + ch) * HWs + hw0 + pxg * 8) = d;
    }
  }
  // ---- phase Q: q0 then q1 through the same slab ----
  {
    short8v wf[4][2];
    load_wfrag(wq, wf);
    f32x4 acc[4];
#pragma unroll
    for (int st = 0; st < 4; ++st) {
      // compute all 4 output tiles for this subtile, hold in regs
      f32x4 a4[4];
#pragma unroll
      for (int mt = 0; mt < 4; ++mt) {
        a4[mt] = __builtin_amdgcn_mfma_f32_16x16x32_bf16(wf[mt][0], bx[st][0], zero, 0, 0, 0);
        a4[mt] = __builtin_amdgcn_mfma_f32_16x16x32_bf16(wf[mt][1], bx[st][1], a4[mt], 0, 0, 0);
      }
      int px = st * 16 + lr;
#pragma unroll
      for (int mt = 0; mt < 2; ++mt)
#pragma unroll
        for (int i = 0; i < 4; ++i)
          S[px * 40 + mt * 16 + lg * 4 + i] = f2bu(a4[mt][i]);
      acc[st] = a4[2];          // stash mt2 per subtile
      // mt3 written after q0 store; stash via acc reuse below
      if (st == 0) { acc[0] = a4[2]; }
      // store mt3 values into spare registers using bx-free approach:
      // simplest: recompute not needed — keep in a second array
      // (handled by a42 below)
      // NOTE: see a42 array
      (void)0;
    }
    // Recompute pass for mt2/mt3 kept simple: redo MFMA for mt2..3 per subtile
    win_store(S, q0);
#pragma unroll
    for (int st = 0; st < 4; ++st) {
      f32x4 a2 = __builtin_amdgcn_mfma_f32_16x16x32_bf16(wf[2][0], bx[st][0], zero, 0, 0, 0);
      a2 = __builtin_amdgcn_mfma_f32_16x16x32_bf16(wf[2][1], bx[st][1], a2, 0, 0, 0);
      f32x4 a3 = __builtin_amdgcn_mfma_f32_16x16x32_bf16(wf[3][0], bx[st][0], zero, 0, 0, 0);
      a3 = __builtin_amdgcn_mfma_f32_16x16x32_bf16(wf[3][1], bx[st][1], a3, 0, 0, 0);
      int px = st * 16 + lr;
#pragma unroll
      for (int i = 0; i < 4; ++i) {
        S[px * 40 + lg * 4 + i] = f2bu(a2[i]);
        S[px * 40 + 16 + lg * 4 + i] = f2bu(a3[i]);
      }
    }
    win_store(S, q1);
  }
  // ---- phase K: k0 window (ch0-31) then ksp spatial (ch32-63) ----
  {
    short8v wf[4][2];
    load_wfrag(wk, wf);
#pragma unroll
    for (int st = 0; st < 4; ++st) {
      int px = st * 16 + lr;
#pragma unroll
      for (int mt = 0; mt < 2; ++mt) {
        f32x4 a4 = __builtin_amdgcn_mfma_f32_16x16x32_bf16(wf[mt][0], bx[st][0], zero, 0, 0, 0);
        a4 = __builtin_amdgcn_mfma_f32_16x16x32_bf16(wf[mt][1], bx[st][1], a4, 0, 0, 0);
#pragma unroll
        for (int i = 0; i < 4; ++i)
          S[px * 40 + mt * 16 + lg * 4 + i] = f2bu(a4[i]);
      }
    }
    win_store(S, k0);
#pragma unroll
    for (int st = 0; st < 4; ++st) {
      int px = st * 16 + lr;
#pragma unroll
      for (int mt = 2; mt < 4; ++mt) {
        f32x4 a4 = __builtin_amdgcn_mfma_f32_16x16x32_bf16(wf[mt][0], bx[st][0], zero, 0, 0, 0);
        a4 = __builtin_amdgcn_mfma_f32_16x16x32_bf16(wf[mt][1], bx[st][1], a4, 0, 0, 0);
#pragma unroll
        for (int i = 0; i < 4; ++i)
          S[((mt - 2) * 16 + lg * 4 + i) * 80 + px] = f2bu(a4[i]);
      }
    }
#pragma unroll
    for (int i = 0; i < 4; ++i) {
      int ch = i * 8 + (lane >> 3), pxg = lane & 7;
      ushort8v d = *(const ushort8v*)(S + ch * 80 + pxg * 8);
      *(ushort8v*)(ksp + ((size_t)b * 32 + ch) * HWs + hw0 + pxg * 8) = d;
    }
  }
  // ---- phase V: v0 window (ch0-31) then vsp spatial (ch32-63) ----
  {
    short8v wf[4][2];
    load_wfrag(wv, wf);
#pragma unroll
    for (int st = 0; st < 4; ++st) {
      int px = st * 16 + lr;
#pragma unroll
      for (int mt = 0; mt < 2; ++mt) {
        f32x4 a4 = __builtin_amdgcn_mfma_f32_16x16x32_bf16(wf[mt][0], bx[st][0], zero, 0, 0, 0);
        a4 = __builtin_amdgcn_mfma_f32_16x16x32_bf16(wf[mt][1], bx[st][1], a4, 0, 0, 0);
#pragma unroll
        for (int i = 0; i < 4; ++i)
          S[px * 40 + mt * 16 + lg * 4 + i] = f2bu(a4[i]);
      }
    }
    win_store(S, v0);
#pragma unroll
    for (int st = 0; st < 4; ++st) {
      int px = st * 16 + lr;
#pragma unroll
      for (int mt = 2; mt < 4; ++mt) {
        f32x4 a4 = __builtin_amdgcn_mfma_f32_16x16x32_bf16(wf[mt][0], bx[st][0], zero, 0, 0, 0);
        a4 = __builtin_amdgcn_mfma_f32_16x16x32_bf16(wf[mt][1], bx[st][1], a4, 0, 0, 0);
#pragma unroll
        for (int i = 0; i < 4; ++i)
          S[((mt - 2) * 16 + lg * 4 + i) * 80 + px] = f2bu(a4[i]);
      }
    }
#pragma unroll
    for (int i = 0; i < 4; ++i) {
      int ch = i * 8 + (lane >> 3), pxg = lane & 7;
      ushort8v d = *(const ushort8v*)(S + ch * 80 + pxg * 8);
      *(ushort8v*)(vsp + ((size_t)b * 32 + ch) * HWs + hw0 + pxg * 8) = d;
    }
  }
}

// ---- K2: depthwise 3x3 + bias, 16 px/thread, vectorized rows ----
__global__ __launch_bounds__(256) void dw_kernel(
    const unsigned short* __restrict__ x, const float* __restrict__ dww,
    const float* __restrict__ dwb, unsigned short* __restrict__ x1,
    float* __restrict__ pool) {
  int tid = threadIdx.x;
  int tx = tid & 15, ty = tid >> 4;
  int h = blockIdx.x * 16 + ty;
  int c = blockIdx.y, b = blockIdx.z;
  const unsigned short* xp = x + ((size_t)b * C + c) * HWs;
  float kk[9];
#pragma unroll
  for (int i = 0; i < 9; ++i) kk[i] = dww[c * 9 + i];
  int w0 = tx * 16;
  float acc[16];
  float bias = dwb[c];
#pragma unroll
  for (int i = 0; i < 16; ++i) acc[i] = bias;
#pragma unroll
  for (int dr = 0; dr < 3; ++dr) {
    int hh = h + dr - 1;
    if (hh < 0 || hh >= H) continue;
    const unsigned short* rp = xp + hh * W;
    ushort8v r0 = *(const ushort8v*)(rp + w0);
    ushort8v r1 = *(const ushort8v*)(rp + w0 + 8);
    float p[18];
    p[0] = (w0 > 0) ? bu2f(rp[w0 - 1]) : 0.f;
    p[17] = (w0 + 16 < W) ? bu2f(rp[w0 + 16]) : 0.f;
#pragma unroll
    for (int i = 0; i < 8; ++i) { p[1 + i] = bu2f(r0[i]); p[9 + i] = bu2f(r1[i]); }
    float k0 = kk[dr * 3], k1 = kk[dr * 3 + 1], k2 = kk[dr * 3 + 2];
#pragma unroll
    for (int i = 0; i < 16; ++i)
      acc[i] += k0 * p[i] + k1 * p[i + 1] + k2 * p[i + 2];
  }
  ushort8v o0, o1;
  float s = 0.f;
#pragma unroll
  for (int i = 0; i < 8; ++i) { o0[i] = f2bu(acc[i]); o1[i] = f2bu(acc[i + 8]); }
#pragma unroll
  for (int i = 0; i < 16; ++i) s += acc[i];
  size_t ob = ((size_t)b * C + c) * HWs + h * W + w0;
  *(ushort8v*)(x1 + ob) = o0;
  *(ushort8v*)(x1 + ob + 8) = o1;
#pragma unroll
  for (int off = 32; off > 0; off >>= 1) s += __shfl_down(s, off, 64);
  __shared__ float red[4];
  if ((tid & 63) == 0) red[tid >> 6] = s;
  __syncthreads();
  if (tid == 0) atomicAdd(&pool[b * C + c], red[0] + red[1] + red[2] + red[3]);
}

// ---- K3: ECA channel attention ----
__global__ __launch_bounds__(512) void eca_kernel(
    const float* __restrict__ pool, const float* __restrict__ w1,
    const float* __restrict__ w2, const float* __restrict__ w3,
    const float* __restrict__ wc, float* __restrict__ ca) {
  int tid = threadIdx.x;
  int b = tid >> 6, c = tid & 63;
  __shared__ float m[8][64], t1[8][64], t2[8][64], t3[8][64];
  m[b][c] = pool[tid] * (1.f / HWs);
  __syncthreads();
  auto gm = [&](int cc) -> float { return (cc >= 0 && cc < 64) ? m[b][cc] : 0.f; };
  t1[b][c] = w1[0] * gm(c - 1) + w1[1] * gm(c) + w1[2] * gm(c + 1);
  t2[b][c] = w2[0] * gm(c - 2) + w2[1] * gm(c) + w2[2] * gm(c + 2);
  t3[b][c] = w3[0] * gm(c - 4) + w3[1] * gm(c) + w3[2] * gm(c + 4);
  __syncthreads();
  auto g1 = [&](int cc) -> float { return (cc >= 0 && cc < 64) ? t1[b][cc] : 0.f; };
  auto g2 = [&](int cc) -> float { return (cc >= 0 && cc < 64) ? t2[b][cc] : 0.f; };
  auto g3 = [&](int cc) -> float { return (cc >= 0 && cc < 64) ? t3[b][cc] : 0.f; };
  float z = 0.f;
#pragma unroll
  for (int k = 0; k < 3; ++k) {
    z += wc[0 * 3 + k] * g1(c + k - 1);
    z += wc[1 * 3 + k] * g2(c + k - 1);
    z += wc[2 * 3 + k] * g3(c + k - 1);
  }
  ca[tid] = 1.f / (1.f + __expf(-z));
}

// ---- K5: 2x2 stride-2 downsample, vectorized loads;
// kdw -> [win][16tok][32ch], vdw -> [win][32ch][16tok] ----
__global__ __launch_bounds__(256) void down_kernel(
    const unsigned short* __restrict__ ksp, const unsigned short* __restrict__ vsp,
    const float* __restrict__ dw, const float* __restrict__ db,
    unsigned short* __restrict__ kdw, unsigned short* __restrict__ vdw) {
  int t = blockIdx.x * 256 + threadIdx.x;   // < 1048576
  int wxd = t & 31, i = (t >> 5) & 127, c = (t >> 12) & 31, b = t >> 17;
  const unsigned short* kp = ksp + ((size_t)b * 32 + c) * HWs;
  const unsigned short* vp = vsp + ((size_t)b * 32 + c) * HWs;
  float w00 = dw[c * 4], w01 = dw[c * 4 + 1], w10 = dw[c * 4 + 2], w11 = dw[c * 4 + 3];
  float bias = db[c];
  int rowa = (2 * i) * W, rowb = rowa + W;
  int c0a = (8 * wxd + 4) & 255, c0b = (8 * wxd + 8) & 255;
  ushort4v ka0 = *(const ushort4v*)(kp + rowa + c0a);
  ushort4v ka1 = *(const ushort4v*)(kp + rowa + c0b);
  ushort4v kb0 = *(const ushort4v*)(kp + rowb + c0a);
  ushort4v kb1 = *(const ushort4v*)(kp + rowb + c0b);
  ushort4v va0 = *(const ushort4v*)(vp + rowa + c0a);
  ushort4v va1 = *(const ushort4v*)(vp + rowa + c0b);
  ushort4v vb0 = *(const ushort4v*)(vp + rowb + c0a);
  ushort4v vb1 = *(const ushort4v*)(vp + rowb + c0b);
  int rr = (i - 2) & 127;
  size_t winb = ((size_t)(b * 1024 + (rr >> 2) * 32 + wxd)) * 512;
  int tokrow = (rr & 3) * 4;
  ushort4v hk, hv;
#pragma unroll
  for (int tx = 0; tx < 4; ++tx) {
    float k00, k01, k10, k11, v00, v01, v10, v11;
    if (tx < 2) {
      k00 = bu2f(ka0[2 * tx]); k01 = bu2f(ka0[2 * tx + 1]);
      k10 = bu2f(kb0[2 * tx]); k11 = bu2f(kb0[2 * tx + 1]);
      v00 = bu2f(va0[2 * tx]); v01 = bu2f(va0[2 * tx + 1]);
      v10 = bu2f(vb0[2 * tx]); v11 = bu2f(vb0[2 * tx + 1]);
    } else {
      k00 = bu2f(ka1[2 * (tx - 2)]); k01 = bu2f(ka1[2 * (tx - 2) + 1]);
      k10 = bu2f(kb1[2 * (tx - 2)]); k11 = bu2f(kb1[2 * (tx - 2) + 1]);
      v00 = bu2f(va1[2 * (tx - 2)]); v01 = bu2f(va1[2 * (tx - 2) + 1]);
      v10 = bu2f(vb1[2 * (tx - 2)]); v11 = bu2f(vb1[2 * (tx - 2) + 1]);
    }
    hk[tx] = f2bu(w00 * k00 + w01 * k01 + w10 * k10 + w11 * k11 + bias);
    hv[tx] = f2bu(w00 * v00 + w01 * v01 + w10 * v10 + w11 * v11 + bias);
  }
  *(ushort4v*)(vdw + winb + (size_t)c * 16 + tokrow) = hv;
#pragma unroll
  for (int tx = 0; tx < 4; ++tx)
    kdw[winb + (size_t)(tokrow + tx) * 32 + c] = hk[tx];
}

// ---- K6: branch 0 window attention via MFMA; block-cooperative 64B y-stores ----
__global__ __launch_bounds__(256) void attn0_kernel(
    const unsigned short* __restrict__ q0, const unsigned short* __restrict__ k0,
    const unsigned short* __restrict__ v0, const float* __restrict__ ca,
    unsigned short* __restrict__ y) {
  __shared__ unsigned short zs[4][32][72];
  int tid = threadIdx.x;
  int lane = tid & 63, wid = tid >> 6;
  int lr = lane & 15, lg = lane >> 4;
  int widx = blockIdx.x * 4 + wid;
  int b = widx >> 10;
  unsigned short* zw = &zs[wid][0][0];
  float cav[8];
#pragma unroll
  for (int mt = 0; mt < 2; ++mt)
#pragma unroll
    for (int r2 = 0; r2 < 4; ++r2)
      cav[mt * 4 + r2] = ca[b * 64 + mt * 16 + lg * 4 + r2];
  {
    const unsigned short* vp = v0 + (size_t)widx * 2048 + (size_t)lane * 32;
#pragma unroll
    for (int j2 = 0; j2 < 4; ++j2) {
      ushort8v vv = *(const ushort8v*)(vp + j2 * 8);
#pragma unroll
      for (int i = 0; i < 8; ++i) zw[(j2 * 8 + i) * 72 + lane] = vv[i];
    }
  }
  const unsigned short* kw = k0 + (size_t)widx * 2048;
  const unsigned short* qw = q0 + (size_t)widx * 2048;
  short8v kf[4], qf[4];
#pragma unroll
  for (int kt = 0; kt < 4; ++kt) {
    ushort4v a = *(const ushort4v*)(kw + (kt * 16 + lr) * 32 + lg * 4);
    ushort4v b2 = *(const ushort4v*)(kw + (kt * 16 + lr) * 32 + lg * 4 + 16);
    kf[kt] = pack2(a, b2);
  }
#pragma unroll
  for (int qt = 0; qt < 4; ++qt) {
    ushort4v a = *(const ushort4v*)(qw + (qt * 16 + lr) * 32 + lg * 4);
    ushort4v b2 = *(const ushort4v*)(qw + (qt * 16 + lr) * 32 + lg * 4 + 16);
    qf[qt] = pack2(a, b2);
  }
  __syncthreads();
  short8v va[2][2];
#pragma unroll
  for (int mt = 0; mt < 2; ++mt)
#pragma unroll
    for (int ck = 0; ck < 2; ++ck) {
      ushort4v a = *(const ushort4v*)&zw[(mt * 16 + lr) * 72 + ck * 32 + lg * 4];
      ushort4v b2 = *(const ushort4v*)&zw[(mt * 16 + lr) * 72 + ck * 32 + lg * 4 + 16];
      va[mt][ck] = pack2(a, b2);
    }
  f32x4 zero = {0.f, 0.f, 0.f, 0.f};
#pragma unroll
  for (int qt = 0; qt < 4; ++qt) {
    f32x4 st[4];
#pragma unroll
    for (int kt = 0; kt < 4; ++kt)
      st[kt] = __builtin_amdgcn_mfma_f32_16x16x32_bf16(kf[kt], qf[qt], zero, 0, 0, 0);
    float mx = -1e30f;
#pragma unroll
    for (int kt = 0; kt < 4; ++kt)
#pragma unroll
      for (int r2 = 0; r2 < 4; ++r2) mx = fmaxf(mx, st[kt][r2]);
    mx = fmaxf(mx, __shfl_xor(mx, 16, 64));
    mx = fmaxf(mx, __shfl_xor(mx, 32, 64));
    float sum = 0.f;
#pragma unroll
    for (int kt = 0; kt < 4; ++kt)
#pragma unroll
      for (int r2 = 0; r2 < 4; ++r2) {
        float e = __expf(SCALE * (st[kt][r2] - mx));
        st[kt][r2] = e;
        sum += e;
      }
    sum += __shfl_xor(sum, 16, 64);
    sum += __shfl_xor(sum, 32, 64);
    float inv = 1.f / sum;
    short8v pb[2];
#pragma unroll
    for (int ck = 0; ck < 2; ++ck)
#pragma unroll
      for (int j = 0; j < 8; ++j)
        pb[ck][j] = (short)f2bu(st[ck * 2 + (j >> 2)][j & 3]);
#pragma unroll
    for (int mt = 0; mt < 2; ++mt) {
      f32x4 yt = __builtin_amdgcn_mfma_f32_16x16x32_bf16(va[mt][0], pb[0], zero, 0, 0, 0);
      yt = __builtin_amdgcn_mfma_f32_16x16x32_bf16(va[mt][1], pb[1], yt, 0, 0, 0);
#pragma unroll
      for (int r2 = 0; r2 < 4; ++r2)
        zw[(mt * 16 + lg * 4 + r2) * 72 + qt * 16 + lr] = f2bu(yt[r2] * inv * cav[mt * 4 + r2]);
    }
  }
  __syncthreads();
  int widx0 = blockIdx.x * 4;
  int b0 = widx0 >> 10, wy0 = (widx0 >> 5) & 31, wxb = widx0 & 31;
#pragma unroll
  for (int pass = 0; pass < 4; ++pass) {
    int sub = tid & 3, pair = tid >> 2;
    int ch = pair & 31;
    int row = pass * 2 + (pair >> 5);
    ushort8v t8 = *(const ushort8v*)&zs[sub][ch][row * 8];
    int r2 = (wy0 * 8 + row + 4) & 255;
    int colb = wxb * 8 + 4 + sub * 8;
    size_t yb = ((size_t)b0 * C + ch) * HWs + (size_t)r2 * W;
    if (colb <= 248) {
      *(ushort8v*)(y + yb + colb) = t8;
    } else {
      ushort4v lo, hi;
#pragma unroll
      for (int i = 0; i < 4; ++i) { lo[i] = t8[i]; hi[i] = t8[4 + i]; }
      *(ushort4v*)(y + yb + 252) = lo;
      *(ushort4v*)(y + yb) = hi;
    }
  }
}

// ---- K7: branch 1 via MFMA (16 keys, zero-padded slots; ca on output) ----
__global__ __launch_bounds__(256) void attn1_kernel(
    const unsigned short* __restrict__ q1, const unsigned short* __restrict__ kdw,
    const unsigned short* __restrict__ vdw, const float* __restrict__ ca,
    unsigned short* __restrict__ y) {
  __shared__ unsigned short zs[4][32][72];
  int tid = threadIdx.x;
  int lane = tid & 63, wid = tid >> 6;
  int lr = lane & 15, lg = lane >> 4;
  int widx = blockIdx.x * 4 + wid;
  int b = widx >> 10;
  unsigned short* zw = &zs[wid][0][0];
  float cav[8];
#pragma unroll
  for (int mt = 0; mt < 2; ++mt)
#pragma unroll
    for (int r2 = 0; r2 < 4; ++r2)
      cav[mt * 4 + r2] = ca[b * 64 + 32 + mt * 16 + lg * 4 + r2];
  short8v kfr;
  {
    ushort4v a = *(const ushort4v*)(kdw + (size_t)widx * 512 + lr * 32 + lg * 4);
    ushort4v b2 = *(const ushort4v*)(kdw + (size_t)widx * 512 + lr * 32 + lg * 4 + 16);
    kfr = pack2(a, b2);
  }
  short8v va[2];
#pragma unroll
  for (int mt = 0; mt < 2; ++mt) {
    ushort4v a = *(const ushort4v*)(vdw + (size_t)widx * 512 + (mt * 16 + lr) * 16 + lg * 4);
    short8v t;
#pragma unroll
    for (int i = 0; i < 4; ++i) { t[i] = (short)a[i]; t[4 + i] = 0; }
    va[mt] = t;
  }
  const unsigned short* qw = q1 + (size_t)widx * 2048;
  short8v qf[4];
#pragma unroll
  for (int qt = 0; qt < 4; ++qt) {
    ushort4v a = *(const ushort4v*)(qw + (qt * 16 + lr) * 32 + lg * 4);
    ushort4v b2 = *(const ushort4v*)(qw + (qt * 16 + lr) * 32 + lg * 4 + 16);
    qf[qt] = pack2(a, b2);
  }
  f32x4 zero = {0.f, 0.f, 0.f, 0.f};
#pragma unroll
  for (int qt = 0; qt < 4; ++qt) {
    f32x4 st = __builtin_amdgcn_mfma_f32_16x16x32_bf16(kfr, qf[qt], zero, 0, 0, 0);
    float mx = fmaxf(fmaxf(st[0], st[1]), fmaxf(st[2], st[3]));
    mx = fmaxf(mx, __shfl_xor(mx, 16, 64));
    mx = fmaxf(mx, __shfl_xor(mx, 32, 64));
    float sum = 0.f;
#pragma unroll
    for (int r2 = 0; r2 < 4; ++r2) {
      float e = __expf(SCALE * (st[r2] - mx));
      st[r2] = e;
      sum += e;
    }
    sum += __shfl_xor(sum, 16, 64);
    sum += __shfl_xor(sum, 32, 64);
    float inv = 1.f / sum;
    short8v pb;
#pragma unroll
    for (int j = 0; j < 4; ++j) { pb[j] = (short)f2bu(st[j]); pb[4 + j] = 0; }
#pragma unroll
    for (int mt = 0; mt < 2; ++mt) {
      f32x4 yt = __builtin_amdgcn_mfma_f32_16x16x32_bf16(va[mt], pb, zero, 0, 0, 0);
#pragma unroll
      for (int r2 = 0; r2 < 4; ++r2)
        zw[(mt * 16 + lg * 4 + r2) * 72 + qt * 16 + lr] = f2bu(yt[r2] * inv * cav[mt * 4 + r2]);
    }
  }
  __syncthreads();
  int widx0 = blockIdx.x * 4;
  int b0 = widx0 >> 10, wy0 = (widx0 >> 5) & 31, wxb = widx0 & 31;
#pragma unroll
  for (int pass = 0; pass < 4; ++pass) {
    int sub = tid & 3, pair = tid >> 2;
    int ch = pair & 31;
    int row = pass * 2 + (pair >> 5);
    ushort8v t8 = *(const ushort8v*)&zs[sub][ch][row * 8];
    int r2 = (wy0 * 8 + row + 4) & 255;
    int colb = wxb * 8 + 4 + sub * 8;
    size_t yb = ((size_t)b0 * C + 32 + ch) * HWs + (size_t)r2 * W;
    if (colb <= 248) {
      *(ushort8v*)(y + yb + colb) = t8;
    } else {
      ushort4v lo, hi;
#pragma unroll
      for (int i = 0; i < 4; ++i) { lo[i] = t8[i]; hi[i] = t8[4 + i]; }
      *(ushort4v*)(y + yb + 252) = lo;
      *(ushort4v*)(y + yb) = hi;
    }
  }
}

// ---- K8 (R8 version, empirically best): fused spatial gate +
// output projection (MFMA) + residual; grid-stride x4, block-coop LDS
// staging with b128 writes, 4 barriers/iter. ----
__global__ __launch_bounds__(256) void final_mfma_kernel(
    const unsigned short* __restrict__ y, const unsigned short* __restrict__ x1,
    const float* __restrict__ x0, const float* __restrict__ sa_w,
    const float* __restrict__ sa_b, const float* __restrict__ po_w,
    const float* __restrict__ po_b, float* __restrict__ out) {
  __shared__ unsigned short zs[64][72];
  __shared__ float part[4][64];
  __shared__ float sgs[64];
  int tid = threadIdx.x;
  int lane = tid & 63, wid = tid >> 6;
  int lr = lane & 15, lg = lane >> 4;
  short8v ap[4][2];
#pragma unroll
  for (int mt = 0; mt < 4; ++mt)
#pragma unroll
    for (int ks = 0; ks < 2; ++ks) {
      int rowoff = (mt * 16 + lr) * 64 + ks * 32 + lg * 4;
      short8v tt;
#pragma unroll
      for (int j = 0; j < 8; ++j) {
        int kj = (j & 3) + 16 * (j >> 2);
        tt[j] = (short)f2bu(po_w[rowoff + kj]);
      }
      ap[mt][ks] = tt;
    }
  int cc = tid >> 2, qx = (tid & 3) * 16;
  const int NBLK = NPIX / 64;
  for (int blk = blockIdx.x; blk < NBLK; blk += gridDim.x) {
    int p0 = blk * 64;
    int b = p0 >> 16, hw0 = p0 & (HWs - 1);
    size_t rbase = (size_t)b * C * HWs + (size_t)cc * HWs + hw0 + qx;
    ushort8v y0 = *(const ushort8v*)(y + rbase);
    ushort8v y1 = *(const ushort8v*)(y + rbase + 8);
    ushort8v a0 = *(const ushort8v*)(x1 + rbase);
    ushort8v a1 = *(const ushort8v*)(x1 + rbase + 8);
    *(ushort8v*)&zs[cc][qx] = y0;
    *(ushort8v*)&zs[cc][qx + 8] = y1;
    __syncthreads();
    {
      int p = tid & 63, qr = tid >> 6;
      float s = 0.f;
#pragma unroll
      for (int c2 = 0; c2 < 16; ++c2)
        s += sa_w[qr * 16 + c2] * bu2f(zs[qr * 16 + c2][p]);
      part[qr][p] = s;
    }
    __syncthreads();
    if (tid < 64) {
      float sd = part[0][tid] + part[1][tid] + part[2][tid] + part[3][tid] + sa_b[0];
      sgs[tid] = 1.f / (1.f + __expf(-sd));
    }
    __syncthreads();
    {
      ushort8v z0, z1;
#pragma unroll
      for (int i = 0; i < 8; ++i) {
        z0[i] = f2bu(bu2f(y0[i]) + sgs[qx + i] * bu2f(a0[i]));
        z1[i] = f2bu(bu2f(y1[i]) + sgs[qx + 8 + i] * bu2f(a1[i]));
      }
      *(ushort8v*)&zs[cc][qx] = z0;
      *(ushort8v*)&zs[cc][qx + 8] = z1;
    }
    __syncthreads();
    short8v bz[2];
#pragma unroll
    for (int ks = 0; ks < 2; ++ks) {
      short8v tt;
#pragma unroll
      for (int j = 0; j < 8; ++j) {
        int c2 = ks * 32 + lg * 4 + (j & 3) + 16 * (j >> 2);
        tt[j] = (short)zs[c2][wid * 16 + lr];
      }
      bz[ks] = tt;
    }
    f32x4 zero = {0.f, 0.f, 0.f, 0.f};
    f32x4 acc[4];
#pragma unroll
    for (int mt = 0; mt < 4; ++mt) {
      acc[mt] = __builtin_amdgcn_mfma_f32_16x16x32_bf16(ap[mt][0], bz[0], zero, 0, 0, 0);
      acc[mt] = __builtin_amdgcn_mfma_f32_16x16x32_bf16(ap[mt][1], bz[1], acc[mt], 0, 0, 0);
    }
    size_t pbase = (size_t)b * C * HWs + hw0 + wid * 16 + lr;
#pragma unroll
    for (int mt = 0; mt < 4; ++mt)
#pragma unroll
      for (int i = 0; i < 4; ++i) {
        int o = mt * 16 + lg * 4 + i;
        out[pbase + (size_t)o * HWs] = acc[mt][i] + po_b[o] + x0[pbase + (size_t)o * HWs];
      }
    __syncthreads();
  }
}

extern "C" void kernel_launch(void* const* d_in, const int* in_sizes, int n_in,
                              void* d_out, int out_size, void* d_ws, size_t ws_size,
                              hipStream_t stream) {
  const float* x0    = (const float*)d_in[0];
  const float* ln_w  = (const float*)d_in[1];
  const float* ln_b  = (const float*)d_in[2];
  const float* dw_w  = (const float*)d_in[3];
  const float* dw_b  = (const float*)d_in[4];
  const float* ew1   = (const float*)d_in[5];
  const float* ew2   = (const float*)d_in[6];
  const float* ew3   = (const float*)d_in[7];
  const float* ewc   = (const float*)d_in[8];
  const float* wq    = (const float*)d_in[9];
  const float* wk    = (const float*)d_in[10];
  const float* wv    = (const float*)d_in[11];
  const float* dwn_w = (const float*)d_in[12];
  const float* dwn_b = (const float*)d_in[13];
  const float* sa_w  = (const float*)d_in[14];
  const float* sa_b  = (const float*)d_in[15];
  const float* po_w  = (const float*)d_in[16];
  const float* po_b  = (const float*)d_in[17];
  float* out = (float*)d_out;

  char* ws = (char*)d_ws;
  const size_t NB = (size_t)NELEM * sizeof(bf16);
  const size_t NH = NB / 2;
  const size_t NDB = (size_t)NDOWN * sizeof(bf16);
  bf16* xbuf  = (bf16*)(ws);
  bf16* x1buf = (bf16*)(ws + NB);
  unsigned short* q0b  = (unsigned short*)(ws + 2 * NB);
  unsigned short* q1b  = (unsigned short*)(ws + 2 * NB + NH);
  unsigned short* k0b  = (unsigned short*)(ws + 3 * NB);
  unsigned short* v0b  = (unsigned short*)(ws + 3 * NB + NH);
  unsigned short* kspb = (unsigned short*)(ws + 4 * NB);
  unsigned short* vspb = (unsigned short*)(ws + 4 * NB + NH);
  unsigned short* kdwb = (unsigned short*)(ws + 5 * NB);
  unsigned short* vdwb = (unsigned short*)(ws + 5 * NB + NDB);
  float* pool = (float*)(ws + 5 * NB + 2 * NDB);
  float* cabuf = pool + B * C;
  bf16* ybuf = xbuf;  // x dead after dw; reuse for attention output

  hipMemsetAsync(pool, 0, B * C * sizeof(float), stream);
  qkv_ln_kernel<<<2048, 256, 0, stream>>>(x0, ln_w, ln_b, wq, wk, wv,
                                          (unsigned short*)xbuf, q0b, q1b, k0b, v0b,
                                          kspb, vspb);
  dw_kernel<<<dim3(16, C, B), 256, 0, stream>>>((const unsigned short*)xbuf, dw_w, dw_b,
                                                (unsigned short*)x1buf, pool);
  eca_kernel<<<1, 512, 0, stream>>>(pool, ew1, ew2, ew3, ewc, cabuf);
  down_kernel<<<4096, 256, 0, stream>>>(kspb, vspb, dwn_w, dwn_b, kdwb, vdwb);
  attn0_kernel<<<2048, 256, 0, stream>>>(q0b, k0b, v0b, cabuf, (unsigned short*)ybuf);
  attn1_kernel<<<2048, 256, 0, stream>>>(q1b, kdwb, vdwb, cabuf, (unsigned short*)ybuf);
  final_mfma_kernel<<<2048, 256, 0, stream>>>((const unsigned short*)ybuf,
                                              (const unsigned short*)x1buf, x0,
                                              sa_w, sa_b, po_w, po_b, out);
}

// Round 16
// 336.905 us; speedup vs baseline: 1.0305x; 1.0305x over previous
//
#include <hip/hip_runtime.h>
#include <hip/hip_bf16.h>

using bf16 = __hip_bfloat16;

constexpr int B = 8, C = 64, H = 256, W = 256;
constexpr int HWs = H * W;               // 65536
constexpr int NPIX = B * H * W;          // 524288
constexpr long long NELEM = (long long)B * C * H * W;  // 33554432
constexpr int CS = 32;
constexpr int Hd = 128, Wd = 128;
constexpr int HWd = Hd * Wd;             // 16384
constexpr int NDOWN = B * CS * HWd;      // 4194304
constexpr float EPS = 1e-6f;
constexpr float SCALE = 0.17677669529663687f;  // 32^-0.5

typedef __attribute__((ext_vector_type(8))) short short8v;
typedef __attribute__((ext_vector_type(8))) unsigned short ushort8v;
typedef __attribute__((ext_vector_type(4))) unsigned short ushort4v;
typedef __attribute__((ext_vector_type(4))) float f32x4;

__device__ __forceinline__ float b2f(bf16 v) { return __bfloat162float(v); }
__device__ __forceinline__ bf16 f2b(float v) { return __float2bfloat16(v); }
__device__ __forceinline__ unsigned short f2bu(float v) {
  bf16 t = __float2bfloat16(v);
  unsigned short u;
  __builtin_memcpy(&u, &t, 2);
  return u;
}
__device__ __forceinline__ float bu2f(unsigned short u) {
  bf16 t;
  __builtin_memcpy(&t, &u, 2);
  return __bfloat162float(t);
}
__device__ __forceinline__ short8v pack2(ushort4v a, ushort4v b) {
  short8v r;
  r[0] = (short)a[0]; r[1] = (short)a[1]; r[2] = (short)a[2]; r[3] = (short)a[3];
  r[4] = (short)b[0]; r[5] = (short)b[1]; r[6] = (short)b[2]; r[7] = (short)b[3];
  return r;
}

// ---- K1 (R14 version, empirically best ~110 µs): fused LayerNorm + q/k/v
// MFMA projections with DENSE writes; two per-wave slabs. ----
__global__ __launch_bounds__(256) void qkv_ln_kernel(
    const float* __restrict__ x0, const float* __restrict__ lnw,
    const float* __restrict__ lnb, const float* __restrict__ wq,
    const float* __restrict__ wk, const float* __restrict__ wv,
    unsigned short* __restrict__ xo, unsigned short* __restrict__ q0,
    unsigned short* __restrict__ q1, unsigned short* __restrict__ k0,
    unsigned short* __restrict__ v0, unsigned short* __restrict__ ksp,
    unsigned short* __restrict__ vsp) {
  __shared__ unsigned short sA[4][2560];   // [wave] 64px*40 (window-layout slab)
  __shared__ unsigned short sB[4][2560];   // [wave] 32ch*80 or 64px*40 (flex)
  int lane = threadIdx.x & 63, wid = threadIdx.x >> 6;
  int lr = lane & 15, lg = lane >> 4;
  unsigned short* A = &sA[wid][0];
  unsigned short* Bs = &sB[wid][0];
  int seg = blockIdx.x * 4 + wid;          // 0..8191
  int p0 = seg * 64;
  int b = p0 >> 16;
  int hw0 = p0 & (HWs - 1);
  int r = hw0 >> 8, col0 = hw0 & 255;      // col0 multiple of 64
  float lwv[16], lbv[16];
#pragma unroll
  for (int ks = 0; ks < 2; ++ks)
#pragma unroll
    for (int j = 0; j < 8; ++j) {
      int c = ks * 32 + lg * 4 + (j & 3) + 16 * (j >> 2);
      lwv[ks * 8 + j] = lnw[c];
      lbv[ks * 8 + j] = lnb[c];
    }
  short8v bx[4][2];
#pragma unroll
  for (int st = 0; st < 4; ++st) {
    const float* xp = x0 + (size_t)b * C * HWs + hw0 + st * 16 + lr;
    float xv[16];
#pragma unroll
    for (int ks = 0; ks < 2; ++ks)
#pragma unroll
      for (int j = 0; j < 8; ++j) {
        int c = ks * 32 + lg * 4 + (j & 3) + 16 * (j >> 2);
        xv[ks * 8 + j] = xp[(size_t)c * HWs];
      }
    float s = 0.f, s2 = 0.f;
#pragma unroll
    for (int i = 0; i < 16; ++i) { s += xv[i]; s2 += xv[i] * xv[i]; }
    s += __shfl_xor(s, 16, 64); s += __shfl_xor(s, 32, 64);
    s2 += __shfl_xor(s2, 16, 64); s2 += __shfl_xor(s2, 32, 64);
    float mu = s * (1.f / 64);
    float var = s2 * (1.f / 64) - mu * mu;
    float rstd = rsqrtf(var + EPS);
#pragma unroll
    for (int ks = 0; ks < 2; ++ks)
#pragma unroll
      for (int j = 0; j < 8; ++j) {
        float xn = lwv[ks * 8 + j] * ((xv[ks * 8 + j] - mu) * rstd) + lbv[ks * 8 + j];
        bx[st][ks][j] = (short)f2bu(xn);
      }
  }
  int rr = (r - 4) & 255;
  int tokr = (rr & 7) * 8;
  int wrow = b * 1024 + (rr >> 3) * 32;
  auto win_store = [&](const unsigned short* src, unsigned short* dst) {
#pragma unroll
    for (int i = 0; i < 4; ++i) {
      int g = i * 4 + (lane >> 4);
      int tl = (lane >> 2) & 3, ch8 = lane & 3;
      int px = g * 4 + tl;
      int ccw = (col0 + px - 4) & 255;
      size_t wb = (size_t)(wrow + (ccw >> 3)) * 2048 +
                  (size_t)(tokr + (ccw & 7)) * 32 + ch8 * 8;
      ushort8v d = *(const ushort8v*)(src + px * 40 + ch8 * 8);
      *(ushort8v*)(dst + wb) = d;
    }
  };
  auto load_wfrag = [&](const float* wsrc, short8v wf[4][2]) {
#pragma unroll
    for (int mt = 0; mt < 4; ++mt)
#pragma unroll
      for (int ks = 0; ks < 2; ++ks) {
        int rowoff = (mt * 16 + lr) * 64 + ks * 32 + lg * 4;
        short8v t;
#pragma unroll
        for (int j = 0; j < 8; ++j) {
          int kj = (j & 3) + 16 * (j >> 2);
          t[j] = (short)f2bu(wsrc[rowoff + kj]);
        }
        wf[mt][ks] = t;
      }
  };
  f32x4 zero = {0.f, 0.f, 0.f, 0.f};
#pragma unroll
  for (int half = 0; half < 2; ++half) {
#pragma unroll
    for (int st = 0; st < 4; ++st) {
      int px = st * 16 + lr;
#pragma unroll
      for (int j = 0; j < 8; ++j) {
        int c = lg * 4 + (j & 3) + 16 * (j >> 2);
        Bs[c * 80 + px] = (unsigned short)bx[st][half][j];
      }
    }
#pragma unroll
    for (int i = 0; i < 4; ++i) {
      int ch = i * 8 + (lane >> 3), pxg = lane & 7;
      ushort8v d = *(const ushort8v*)(Bs + ch * 80 + pxg * 8);
      *(ushort8v*)(xo + ((size_t)b * 64 + half * 32 + ch) * HWs + hw0 + pxg * 8) = d;
    }
  }
  {
    short8v wf[4][2];
    load_wfrag(wq, wf);
#pragma unroll
    for (int st = 0; st < 4; ++st) {
      f32x4 acc[4];
#pragma unroll
      for (int mt = 0; mt < 4; ++mt) {
        acc[mt] = __builtin_amdgcn_mfma_f32_16x16x32_bf16(wf[mt][0], bx[st][0], zero, 0, 0, 0);
        acc[mt] = __builtin_amdgcn_mfma_f32_16x16x32_bf16(wf[mt][1], bx[st][1], acc[mt], 0, 0, 0);
      }
      int px = st * 16 + lr;
#pragma unroll
      for (int mt = 0; mt < 2; ++mt)
#pragma unroll
        for (int i = 0; i < 4; ++i)
          A[px * 40 + mt * 16 + lg * 4 + i] = f2bu(acc[mt][i]);
#pragma unroll
      for (int mt = 2; mt < 4; ++mt)
#pragma unroll
        for (int i = 0; i < 4; ++i)
          Bs[px * 40 + (mt - 2) * 16 + lg * 4 + i] = f2bu(acc[mt][i]);
    }
    win_store(A, q0);
    win_store(Bs, q1);
  }
  {
    short8v wf[4][2];
    load_wfrag(wk, wf);
#pragma unroll
    for (int st = 0; st < 4; ++st) {
      f32x4 acc[4];
#pragma unroll
      for (int mt = 0; mt < 4; ++mt) {
        acc[mt] = __builtin_amdgcn_mfma_f32_16x16x32_bf16(wf[mt][0], bx[st][0], zero, 0, 0, 0);
        acc[mt] = __builtin_amdgcn_mfma_f32_16x16x32_bf16(wf[mt][1], bx[st][1], acc[mt], 0, 0, 0);
      }
      int px = st * 16 + lr;
#pragma unroll
      for (int mt = 0; mt < 2; ++mt)
#pragma unroll
        for (int i = 0; i < 4; ++i)
          A[px * 40 + mt * 16 + lg * 4 + i] = f2bu(acc[mt][i]);
#pragma unroll
      for (int mt = 2; mt < 4; ++mt)
#pragma unroll
        for (int i = 0; i < 4; ++i)
          Bs[((mt - 2) * 16 + lg * 4 + i) * 80 + px] = f2bu(acc[mt][i]);
    }
    win_store(A, k0);
#pragma unroll
    for (int i = 0; i < 4; ++i) {
      int ch = i * 8 + (lane >> 3), pxg = lane & 7;
      ushort8v d = *(const ushort8v*)(Bs + ch * 80 + pxg * 8);
      *(ushort8v*)(ksp + ((size_t)b * 32 + ch) * HWs + hw0 + pxg * 8) = d;
    }
  }
  {
    short8v wf[4][2];
    load_wfrag(wv, wf);
#pragma unroll
    for (int st = 0; st < 4; ++st) {
      f32x4 acc[4];
#pragma unroll
      for (int mt = 0; mt < 4; ++mt) {
        acc[mt] = __builtin_amdgcn_mfma_f32_16x16x32_bf16(wf[mt][0], bx[st][0], zero, 0, 0, 0);
        acc[mt] = __builtin_amdgcn_mfma_f32_16x16x32_bf16(wf[mt][1], bx[st][1], acc[mt], 0, 0, 0);
      }
      int px = st * 16 + lr;
#pragma unroll
      for (int mt = 0; mt < 2; ++mt)
#pragma unroll
        for (int i = 0; i < 4; ++i)
          A[px * 40 + mt * 16 + lg * 4 + i] = f2bu(acc[mt][i]);
#pragma unroll
      for (int mt = 2; mt < 4; ++mt)
#pragma unroll
        for (int i = 0; i < 4; ++i)
          Bs[((mt - 2) * 16 + lg * 4 + i) * 80 + px] = f2bu(acc[mt][i]);
    }
    win_store(A, v0);
#pragma unroll
    for (int i = 0; i < 4; ++i) {
      int ch = i * 8 + (lane >> 3), pxg = lane & 7;
      ushort8v d = *(const ushort8v*)(Bs + ch * 80 + pxg * 8);
      *(ushort8v*)(vsp + ((size_t)b * 32 + ch) * HWs + hw0 + pxg * 8) = d;
    }
  }
}

// ---- K2+K5 merged: dw (blocks 0..8191) || down (blocks 8192..12287).
// Independent work, one launch -> overlapped execution. ----
__global__ __launch_bounds__(256) void dw_down_kernel(
    const unsigned short* __restrict__ x, const float* __restrict__ dww,
    const float* __restrict__ dwb, unsigned short* __restrict__ x1,
    float* __restrict__ pool,
    const unsigned short* __restrict__ ksp, const unsigned short* __restrict__ vsp,
    const float* __restrict__ dw, const float* __restrict__ db,
    unsigned short* __restrict__ kdw, unsigned short* __restrict__ vdw) {
  __shared__ float red[4];
  int tid = threadIdx.x;
  int blk = blockIdx.x;
  if (blk < 8192) {
    // ---- depthwise 3x3 + bias + pool reduction ----
    int tx = tid & 15, ty = tid >> 4;
    int hb = blk & 15;
    int c = (blk >> 4) & 63;
    int b = blk >> 10;
    int h = hb * 16 + ty;
    const unsigned short* xp = x + ((size_t)b * C + c) * HWs;
    float kk[9];
#pragma unroll
    for (int i = 0; i < 9; ++i) kk[i] = dww[c * 9 + i];
    int w0 = tx * 16;
    float acc[16];
    float bias = dwb[c];
#pragma unroll
    for (int i = 0; i < 16; ++i) acc[i] = bias;
#pragma unroll
    for (int dr = 0; dr < 3; ++dr) {
      int hh = h + dr - 1;
      if (hh < 0 || hh >= H) continue;
      const unsigned short* rp = xp + hh * W;
      ushort8v r0 = *(const ushort8v*)(rp + w0);
      ushort8v r1 = *(const ushort8v*)(rp + w0 + 8);
      float p[18];
      p[0] = (w0 > 0) ? bu2f(rp[w0 - 1]) : 0.f;
      p[17] = (w0 + 16 < W) ? bu2f(rp[w0 + 16]) : 0.f;
#pragma unroll
      for (int i = 0; i < 8; ++i) { p[1 + i] = bu2f(r0[i]); p[9 + i] = bu2f(r1[i]); }
      float k0 = kk[dr * 3], k1 = kk[dr * 3 + 1], k2 = kk[dr * 3 + 2];
#pragma unroll
      for (int i = 0; i < 16; ++i)
        acc[i] += k0 * p[i] + k1 * p[i + 1] + k2 * p[i + 2];
    }
    ushort8v o0, o1;
    float s = 0.f;
#pragma unroll
    for (int i = 0; i < 8; ++i) { o0[i] = f2bu(acc[i]); o1[i] = f2bu(acc[i + 8]); }
#pragma unroll
    for (int i = 0; i < 16; ++i) s += acc[i];
    size_t ob = ((size_t)b * C + c) * HWs + h * W + w0;
    *(ushort8v*)(x1 + ob) = o0;
    *(ushort8v*)(x1 + ob + 8) = o1;
#pragma unroll
    for (int off = 32; off > 0; off >>= 1) s += __shfl_down(s, off, 64);
    if ((tid & 63) == 0) red[tid >> 6] = s;
    __syncthreads();
    if (tid == 0) atomicAdd(&pool[b * C + c], red[0] + red[1] + red[2] + red[3]);
  } else {
    // ---- 2x2 stride-2 downsample ----
    int t = (blk - 8192) * 256 + tid;   // < 1048576
    int wxd = t & 31, i = (t >> 5) & 127, c = (t >> 12) & 31, b = t >> 17;
    const unsigned short* kp = ksp + ((size_t)b * 32 + c) * HWs;
    const unsigned short* vp = vsp + ((size_t)b * 32 + c) * HWs;
    float w00 = dw[c * 4], w01 = dw[c * 4 + 1], w10 = dw[c * 4 + 2], w11 = dw[c * 4 + 3];
    float bias = db[c];
    int rowa = (2 * i) * W, rowb = rowa + W;
    int c0a = (8 * wxd + 4) & 255, c0b = (8 * wxd + 8) & 255;
    ushort4v ka0 = *(const ushort4v*)(kp + rowa + c0a);
    ushort4v ka1 = *(const ushort4v*)(kp + rowa + c0b);
    ushort4v kb0 = *(const ushort4v*)(kp + rowb + c0a);
    ushort4v kb1 = *(const ushort4v*)(kp + rowb + c0b);
    ushort4v va0 = *(const ushort4v*)(vp + rowa + c0a);
    ushort4v va1 = *(const ushort4v*)(vp + rowa + c0b);
    ushort4v vb0 = *(const ushort4v*)(vp + rowb + c0a);
    ushort4v vb1 = *(const ushort4v*)(vp + rowb + c0b);
    int rr = (i - 2) & 127;
    size_t winb = ((size_t)(b * 1024 + (rr >> 2) * 32 + wxd)) * 512;
    int tokrow = (rr & 3) * 4;
    ushort4v hk, hv;
#pragma unroll
    for (int tx = 0; tx < 4; ++tx) {
      float k00, k01, k10, k11, v00, v01, v10, v11;
      if (tx < 2) {
        k00 = bu2f(ka0[2 * tx]); k01 = bu2f(ka0[2 * tx + 1]);
        k10 = bu2f(kb0[2 * tx]); k11 = bu2f(kb0[2 * tx + 1]);
        v00 = bu2f(va0[2 * tx]); v01 = bu2f(va0[2 * tx + 1]);
        v10 = bu2f(vb0[2 * tx]); v11 = bu2f(vb0[2 * tx + 1]);
      } else {
        k00 = bu2f(ka1[2 * (tx - 2)]); k01 = bu2f(ka1[2 * (tx - 2) + 1]);
        k10 = bu2f(kb1[2 * (tx - 2)]); k11 = bu2f(kb1[2 * (tx - 2) + 1]);
        v00 = bu2f(va1[2 * (tx - 2)]); v01 = bu2f(va1[2 * (tx - 2) + 1]);
        v10 = bu2f(vb1[2 * (tx - 2)]); v11 = bu2f(vb1[2 * (tx - 2) + 1]);
      }
      hk[tx] = f2bu(w00 * k00 + w01 * k01 + w10 * k10 + w11 * k11 + bias);
      hv[tx] = f2bu(w00 * v00 + w01 * v01 + w10 * v10 + w11 * v11 + bias);
    }
    *(ushort4v*)(vdw + winb + (size_t)c * 16 + tokrow) = hv;
#pragma unroll
    for (int tx = 0; tx < 4; ++tx)
      kdw[winb + (size_t)(tokrow + tx) * 32 + c] = hk[tx];
  }
}

// ---- K3: ECA channel attention ----
__global__ __launch_bounds__(512) void eca_kernel(
    const float* __restrict__ pool, const float* __restrict__ w1,
    const float* __restrict__ w2, const float* __restrict__ w3,
    const float* __restrict__ wc, float* __restrict__ ca) {
  int tid = threadIdx.x;
  int b = tid >> 6, c = tid & 63;
  __shared__ float m[8][64], t1[8][64], t2[8][64], t3[8][64];
  m[b][c] = pool[tid] * (1.f / HWs);
  __syncthreads();
  auto gm = [&](int cc) -> float { return (cc >= 0 && cc < 64) ? m[b][cc] : 0.f; };
  t1[b][c] = w1[0] * gm(c - 1) + w1[1] * gm(c) + w1[2] * gm(c + 1);
  t2[b][c] = w2[0] * gm(c - 2) + w2[1] * gm(c) + w2[2] * gm(c + 2);
  t3[b][c] = w3[0] * gm(c - 4) + w3[1] * gm(c) + w3[2] * gm(c + 4);
  __syncthreads();
  auto g1 = [&](int cc) -> float { return (cc >= 0 && cc < 64) ? t1[b][cc] : 0.f; };
  auto g2 = [&](int cc) -> float { return (cc >= 0 && cc < 64) ? t2[b][cc] : 0.f; };
  auto g3 = [&](int cc) -> float { return (cc >= 0 && cc < 64) ? t3[b][cc] : 0.f; };
  float z = 0.f;
#pragma unroll
  for (int k = 0; k < 3; ++k) {
    z += wc[0 * 3 + k] * g1(c + k - 1);
    z += wc[1 * 3 + k] * g2(c + k - 1);
    z += wc[2 * 3 + k] * g3(c + k - 1);
  }
  ca[tid] = 1.f / (1.f + __expf(-z));
}

// ---- K6+K7 merged: attn0 (blocks 0..2047) || attn1 (blocks 2048..4095).
// Disjoint channels & outputs; one launch -> overlapped execution. ----
__global__ __launch_bounds__(256) void attn_kernel(
    const unsigned short* __restrict__ q0, const unsigned short* __restrict__ k0,
    const unsigned short* __restrict__ v0, const unsigned short* __restrict__ q1,
    const unsigned short* __restrict__ kdw, const unsigned short* __restrict__ vdw,
    const float* __restrict__ ca, unsigned short* __restrict__ y) {
  __shared__ unsigned short zs[4][32][72];
  int tid = threadIdx.x;
  int lane = tid & 63, wid = tid >> 6;
  int lr = lane & 15, lg = lane >> 4;
  f32x4 zero = {0.f, 0.f, 0.f, 0.f};
  if (blockIdx.x < 2048) {
    // ================= branch 0 =================
    int widx = blockIdx.x * 4 + wid;
    int b = widx >> 10;
    unsigned short* zw = &zs[wid][0][0];
    float cav[8];
#pragma unroll
    for (int mt = 0; mt < 2; ++mt)
#pragma unroll
      for (int r2 = 0; r2 < 4; ++r2)
        cav[mt * 4 + r2] = ca[b * 64 + mt * 16 + lg * 4 + r2];
    {
      const unsigned short* vp = v0 + (size_t)widx * 2048 + (size_t)lane * 32;
#pragma unroll
      for (int j2 = 0; j2 < 4; ++j2) {
        ushort8v vv = *(const ushort8v*)(vp + j2 * 8);
#pragma unroll
        for (int i = 0; i < 8; ++i) zw[(j2 * 8 + i) * 72 + lane] = vv[i];
      }
    }
    const unsigned short* kw = k0 + (size_t)widx * 2048;
    const unsigned short* qw = q0 + (size_t)widx * 2048;
    short8v kf[4], qf[4];
#pragma unroll
    for (int kt = 0; kt < 4; ++kt) {
      ushort4v a = *(const ushort4v*)(kw + (kt * 16 + lr) * 32 + lg * 4);
      ushort4v b2 = *(const ushort4v*)(kw + (kt * 16 + lr) * 32 + lg * 4 + 16);
      kf[kt] = pack2(a, b2);
    }
#pragma unroll
    for (int qt = 0; qt < 4; ++qt) {
      ushort4v a = *(const ushort4v*)(qw + (qt * 16 + lr) * 32 + lg * 4);
      ushort4v b2 = *(const ushort4v*)(qw + (qt * 16 + lr) * 32 + lg * 4 + 16);
      qf[qt] = pack2(a, b2);
    }
    __syncthreads();
    short8v va[2][2];
#pragma unroll
    for (int mt = 0; mt < 2; ++mt)
#pragma unroll
      for (int ck = 0; ck < 2; ++ck) {
        ushort4v a = *(const ushort4v*)&zw[(mt * 16 + lr) * 72 + ck * 32 + lg * 4];
        ushort4v b2 = *(const ushort4v*)&zw[(mt * 16 + lr) * 72 + ck * 32 + lg * 4 + 16];
        va[mt][ck] = pack2(a, b2);
      }
#pragma unroll
    for (int qt = 0; qt < 4; ++qt) {
      f32x4 st[4];
#pragma unroll
      for (int kt = 0; kt < 4; ++kt)
        st[kt] = __builtin_amdgcn_mfma_f32_16x16x32_bf16(kf[kt], qf[qt], zero, 0, 0, 0);
      float mx = -1e30f;
#pragma unroll
      for (int kt = 0; kt < 4; ++kt)
#pragma unroll
        for (int r2 = 0; r2 < 4; ++r2) mx = fmaxf(mx, st[kt][r2]);
      mx = fmaxf(mx, __shfl_xor(mx, 16, 64));
      mx = fmaxf(mx, __shfl_xor(mx, 32, 64));
      float sum = 0.f;
#pragma unroll
      for (int kt = 0; kt < 4; ++kt)
#pragma unroll
        for (int r2 = 0; r2 < 4; ++r2) {
          float e = __expf(SCALE * (st[kt][r2] - mx));
          st[kt][r2] = e;
          sum += e;
        }
      sum += __shfl_xor(sum, 16, 64);
      sum += __shfl_xor(sum, 32, 64);
      float inv = 1.f / sum;
      short8v pb[2];
#pragma unroll
      for (int ck = 0; ck < 2; ++ck)
#pragma unroll
        for (int j = 0; j < 8; ++j)
          pb[ck][j] = (short)f2bu(st[ck * 2 + (j >> 2)][j & 3]);
#pragma unroll
      for (int mt = 0; mt < 2; ++mt) {
        f32x4 yt = __builtin_amdgcn_mfma_f32_16x16x32_bf16(va[mt][0], pb[0], zero, 0, 0, 0);
        yt = __builtin_amdgcn_mfma_f32_16x16x32_bf16(va[mt][1], pb[1], yt, 0, 0, 0);
#pragma unroll
        for (int r2 = 0; r2 < 4; ++r2)
          zw[(mt * 16 + lg * 4 + r2) * 72 + qt * 16 + lr] =
              f2bu(yt[r2] * inv * cav[mt * 4 + r2]);
      }
    }
    __syncthreads();
    int widx0 = blockIdx.x * 4;
    int b0 = widx0 >> 10, wy0 = (widx0 >> 5) & 31, wxb = widx0 & 31;
#pragma unroll
    for (int pass = 0; pass < 4; ++pass) {
      int sub = tid & 3, pair = tid >> 2;
      int ch = pair & 31;
      int row = pass * 2 + (pair >> 5);
      ushort8v t8 = *(const ushort8v*)&zs[sub][ch][row * 8];
      int r2 = (wy0 * 8 + row + 4) & 255;
      int colb = wxb * 8 + 4 + sub * 8;
      size_t yb = ((size_t)b0 * C + ch) * HWs + (size_t)r2 * W;
      if (colb <= 248) {
        *(ushort8v*)(y + yb + colb) = t8;
      } else {
        ushort4v lo, hi;
#pragma unroll
        for (int i = 0; i < 4; ++i) { lo[i] = t8[i]; hi[i] = t8[4 + i]; }
        *(ushort4v*)(y + yb + 252) = lo;
        *(ushort4v*)(y + yb) = hi;
      }
    }
  } else {
    // ================= branch 1 =================
    int bblk = blockIdx.x - 2048;
    int widx = bblk * 4 + wid;
    int b = widx >> 10;
    unsigned short* zw = &zs[wid][0][0];
    float cav[8];
#pragma unroll
    for (int mt = 0; mt < 2; ++mt)
#pragma unroll
      for (int r2 = 0; r2 < 4; ++r2)
        cav[mt * 4 + r2] = ca[b * 64 + 32 + mt * 16 + lg * 4 + r2];
    short8v kfr;
    {
      ushort4v a = *(const ushort4v*)(kdw + (size_t)widx * 512 + lr * 32 + lg * 4);
      ushort4v b2 = *(const ushort4v*)(kdw + (size_t)widx * 512 + lr * 32 + lg * 4 + 16);
      kfr = pack2(a, b2);
    }
    short8v va1[2];
#pragma unroll
    for (int mt = 0; mt < 2; ++mt) {
      ushort4v a = *(const ushort4v*)(vdw + (size_t)widx * 512 + (mt * 16 + lr) * 16 + lg * 4);
      short8v t;
#pragma unroll
      for (int i = 0; i < 4; ++i) { t[i] = (short)a[i]; t[4 + i] = 0; }
      va1[mt] = t;
    }
    const unsigned short* qw = q1 + (size_t)widx * 2048;
    short8v qf[4];
#pragma unroll
    for (int qt = 0; qt < 4; ++qt) {
      ushort4v a = *(const ushort4v*)(qw + (qt * 16 + lr) * 32 + lg * 4);
      ushort4v b2 = *(const ushort4v*)(qw + (qt * 16 + lr) * 32 + lg * 4 + 16);
      qf[qt] = pack2(a, b2);
    }
#pragma unroll
    for (int qt = 0; qt < 4; ++qt) {
      f32x4 st = __builtin_amdgcn_mfma_f32_16x16x32_bf16(kfr, qf[qt], zero, 0, 0, 0);
      float mx = fmaxf(fmaxf(st[0], st[1]), fmaxf(st[2], st[3]));
      mx = fmaxf(mx, __shfl_xor(mx, 16, 64));
      mx = fmaxf(mx, __shfl_xor(mx, 32, 64));
      float sum = 0.f;
#pragma unroll
      for (int r2 = 0; r2 < 4; ++r2) {
        float e = __expf(SCALE * (st[r2] - mx));
        st[r2] = e;
        sum += e;
      }
      sum += __shfl_xor(sum, 16, 64);
      sum += __shfl_xor(sum, 32, 64);
      float inv = 1.f / sum;
      short8v pb;
#pragma unroll
      for (int j = 0; j < 4; ++j) { pb[j] = (short)f2bu(st[j]); pb[4 + j] = 0; }
#pragma unroll
      for (int mt = 0; mt < 2; ++mt) {
        f32x4 yt = __builtin_amdgcn_mfma_f32_16x16x32_bf16(va1[mt], pb, zero, 0, 0, 0);
#pragma unroll
        for (int r2 = 0; r2 < 4; ++r2)
          zw[(mt * 16 + lg * 4 + r2) * 72 + qt * 16 + lr] =
              f2bu(yt[r2] * inv * cav[mt * 4 + r2]);
      }
    }
    __syncthreads();
    int widx0 = bblk * 4;
    int b0 = widx0 >> 10, wy0 = (widx0 >> 5) & 31, wxb = widx0 & 31;
#pragma unroll
    for (int pass = 0; pass < 4; ++pass) {
      int sub = tid & 3, pair = tid >> 2;
      int ch = pair & 31;
      int row = pass * 2 + (pair >> 5);
      ushort8v t8 = *(const ushort8v*)&zs[sub][ch][row * 8];
      int r2 = (wy0 * 8 + row + 4) & 255;
      int colb = wxb * 8 + 4 + sub * 8;
      size_t yb = ((size_t)b0 * C + 32 + ch) * HWs + (size_t)r2 * W;
      if (colb <= 248) {
        *(ushort8v*)(y + yb + colb) = t8;
      } else {
        ushort4v lo, hi;
#pragma unroll
        for (int i = 0; i < 4; ++i) { lo[i] = t8[i]; hi[i] = t8[4 + i]; }
        *(ushort4v*)(y + yb + 252) = lo;
        *(ushort4v*)(y + yb) = hi;
      }
    }
  }
}

// ---- K8 (R8 version, empirically best): fused spatial gate +
// output projection (MFMA) + residual; grid-stride x4, block-coop LDS
// staging with b128 writes, 4 barriers/iter. ----
__global__ __launch_bounds__(256) void final_mfma_kernel(
    const unsigned short* __restrict__ y, const unsigned short* __restrict__ x1,
    const float* __restrict__ x0, const float* __restrict__ sa_w,
    const float* __restrict__ sa_b, const float* __restrict__ po_w,
    const float* __restrict__ po_b, float* __restrict__ out) {
  __shared__ unsigned short zs[64][72];
  __shared__ float part[4][64];
  __shared__ float sgs[64];
  int tid = threadIdx.x;
  int lane = tid & 63, wid = tid >> 6;
  int lr = lane & 15, lg = lane >> 4;
  short8v ap[4][2];
#pragma unroll
  for (int mt = 0; mt < 4; ++mt)
#pragma unroll
    for (int ks = 0; ks < 2; ++ks) {
      int rowoff = (mt * 16 + lr) * 64 + ks * 32 + lg * 4;
      short8v tt;
#pragma unroll
      for (int j = 0; j < 8; ++j) {
        int kj = (j & 3) + 16 * (j >> 2);
        tt[j] = (short)f2bu(po_w[rowoff + kj]);
      }
      ap[mt][ks] = tt;
    }
  int cc = tid >> 2, qx = (tid & 3) * 16;
  const int NBLK = NPIX / 64;
  for (int blk = blockIdx.x; blk < NBLK; blk += gridDim.x) {
    int p0 = blk * 64;
    int b = p0 >> 16, hw0 = p0 & (HWs - 1);
    size_t rbase = (size_t)b * C * HWs + (size_t)cc * HWs + hw0 + qx;
    ushort8v y0 = *(const ushort8v*)(y + rbase);
    ushort8v y1 = *(const ushort8v*)(y + rbase + 8);
    ushort8v a0 = *(const ushort8v*)(x1 + rbase);
    ushort8v a1 = *(const ushort8v*)(x1 + rbase + 8);
    *(ushort8v*)&zs[cc][qx] = y0;
    *(ushort8v*)&zs[cc][qx + 8] = y1;
    __syncthreads();
    {
      int p = tid & 63, qr = tid >> 6;
      float s = 0.f;
#pragma unroll
      for (int c2 = 0; c2 < 16; ++c2)
        s += sa_w[qr * 16 + c2] * bu2f(zs[qr * 16 + c2][p]);
      part[qr][p] = s;
    }
    __syncthreads();
    if (tid < 64) {
      float sd = part[0][tid] + part[1][tid] + part[2][tid] + part[3][tid] + sa_b[0];
      sgs[tid] = 1.f / (1.f + __expf(-sd));
    }
    __syncthreads();
    {
      ushort8v z0, z1;
#pragma unroll
      for (int i = 0; i < 8; ++i) {
        z0[i] = f2bu(bu2f(y0[i]) + sgs[qx + i] * bu2f(a0[i]));
        z1[i] = f2bu(bu2f(y1[i]) + sgs[qx + 8 + i] * bu2f(a1[i]));
      }
      *(ushort8v*)&zs[cc][qx] = z0;
      *(ushort8v*)&zs[cc][qx + 8] = z1;
    }
    __syncthreads();
    short8v bz[2];
#pragma unroll
    for (int ks = 0; ks < 2; ++ks) {
      short8v tt;
#pragma unroll
      for (int j = 0; j < 8; ++j) {
        int c2 = ks * 32 + lg * 4 + (j & 3) + 16 * (j >> 2);
        tt[j] = (short)zs[c2][wid * 16 + lr];
      }
      bz[ks] = tt;
    }
    f32x4 zero = {0.f, 0.f, 0.f, 0.f};
    f32x4 acc[4];
#pragma unroll
    for (int mt = 0; mt < 4; ++mt) {
      acc[mt] = __builtin_amdgcn_mfma_f32_16x16x32_bf16(ap[mt][0], bz[0], zero, 0, 0, 0);
      acc[mt] = __builtin_amdgcn_mfma_f32_16x16x32_bf16(ap[mt][1], bz[1], acc[mt], 0, 0, 0);
    }
    size_t pbase = (size_t)b * C * HWs + hw0 + wid * 16 + lr;
#pragma unroll
    for (int mt = 0; mt < 4; ++mt)
#pragma unroll
      for (int i = 0; i < 4; ++i) {
        int o = mt * 16 + lg * 4 + i;
        out[pbase + (size_t)o * HWs] = acc[mt][i] + po_b[o] + x0[pbase + (size_t)o * HWs];
      }
    __syncthreads();
  }
}

extern "C" void kernel_launch(void* const* d_in, const int* in_sizes, int n_in,
                              void* d_out, int out_size, void* d_ws, size_t ws_size,
                              hipStream_t stream) {
  const float* x0    = (const float*)d_in[0];
  const float* ln_w  = (const float*)d_in[1];
  const float* ln_b  = (const float*)d_in[2];
  const float* dw_w  = (const float*)d_in[3];
  const float* dw_b  = (const float*)d_in[4];
  const float* ew1   = (const float*)d_in[5];
  const float* ew2   = (const float*)d_in[6];
  const float* ew3   = (const float*)d_in[7];
  const float* ewc   = (const float*)d_in[8];
  const float* wq    = (const float*)d_in[9];
  const float* wk    = (const float*)d_in[10];
  const float* wv    = (const float*)d_in[11];
  const float* dwn_w = (const float*)d_in[12];
  const float* dwn_b = (const float*)d_in[13];
  const float* sa_w  = (const float*)d_in[14];
  const float* sa_b  = (const float*)d_in[15];
  const float* po_w  = (const float*)d_in[16];
  const float* po_b  = (const float*)d_in[17];
  float* out = (float*)d_out;

  char* ws = (char*)d_ws;
  const size_t NB = (size_t)NELEM * sizeof(bf16);
  const size_t NH = NB / 2;
  const size_t NDB = (size_t)NDOWN * sizeof(bf16);
  bf16* xbuf  = (bf16*)(ws);
  bf16* x1buf = (bf16*)(ws + NB);
  unsigned short* q0b  = (unsigned short*)(ws + 2 * NB);
  unsigned short* q1b  = (unsigned short*)(ws + 2 * NB + NH);
  unsigned short* k0b  = (unsigned short*)(ws + 3 * NB);
  unsigned short* v0b  = (unsigned short*)(ws + 3 * NB + NH);
  unsigned short* kspb = (unsigned short*)(ws + 4 * NB);
  unsigned short* vspb = (unsigned short*)(ws + 4 * NB + NH);
  unsigned short* kdwb = (unsigned short*)(ws + 5 * NB);
  unsigned short* vdwb = (unsigned short*)(ws + 5 * NB + NDB);
  float* pool = (float*)(ws + 5 * NB + 2 * NDB);
  float* cabuf = pool + B * C;
  bf16* ybuf = xbuf;  // x dead after dw; reuse for attention output

  hipMemsetAsync(pool, 0, B * C * sizeof(float), stream);
  qkv_ln_kernel<<<2048, 256, 0, stream>>>(x0, ln_w, ln_b, wq, wk, wv,
                                          (unsigned short*)xbuf, q0b, q1b, k0b, v0b,
                                          kspb, vspb);
  dw_down_kernel<<<12288, 256, 0, stream>>>((const unsigned short*)xbuf, dw_w, dw_b,
                                            (unsigned short*)x1buf, pool,
                                            kspb, vspb, dwn_w, dwn_b, kdwb, vdwb);
  eca_kernel<<<1, 512, 0, stream>>>(pool, ew1, ew2, ew3, ewc, cabuf);
  attn_kernel<<<4096, 256, 0, stream>>>(q0b, k0b, v0b, q1b, kdwb, vdwb, cabuf,
                                        (unsigned short*)ybuf);
  final_mfma_kernel<<<2048, 256, 0, stream>>>((const unsigned short*)ybuf,
                                              (const unsigned short*)x1buf, x0,
                                              sa_w, sa_b, po_w, po_b, out);
}